// Round 1
// baseline (13260.829 us; speedup 1.0000x reference)
//
#include <hip/hip_runtime.h>
#include <math.h>

// ---------------- problem constants ----------------
#define NEDU  1024
#define LTOK  20
#define CW    330     // 300 word + 30 pos
#define HDIM  256
#define FEAT  930
#define MSLOT 1026    // N_EDUS + 2

// ---------------- workspace layout (32-bit word offsets) ----------------
#define O_WCATT 0
#define SZ_WCATT (330*600)
#define O_F     (O_WCATT + SZ_WCATT)
#define SZ_F    (NEDU*FEAT)
// loss partials overlap WCATT+F (both dead once parse runs): 2048 rows x 512 floats
#define O_LOSSP 0
#define SZ_LOSSP (2048*512)
#define O_BUFH  (O_F + SZ_F)
#define SZ_BUF  (MSLOT*HDIM)
#define O_BUFC  (O_BUFH + SZ_BUF)
#define O_STKT  (O_BUFC + SZ_BUF)          // tagged stack [2 parity][MSLOT][HDIM] u32
#define O_THT   (O_STKT + 2*SZ_BUF)        // tagged tracker h [2 parity][HDIM] u32
#define O_PART  (O_THT + 2*HDIM)           // 64 doubles loss partials (128 words)
#define NZERO   ((2*MSLOT + 2) * HDIM)     // stkT(2 par) + thT(2 par), zeros w/ tag 0

typedef unsigned long long u64;

#define AG __HIP_MEMORY_SCOPE_AGENT
__device__ __forceinline__ u64 aload64(const u64* p) {
  return __hip_atomic_load(p, __ATOMIC_RELAXED, AG);
}
__device__ __forceinline__ void astore(unsigned* p, unsigned v) {
  __hip_atomic_store(p, v, __ATOMIC_RELAXED, AG);
}
__device__ __forceinline__ unsigned tagbits(float v, unsigned ver) {
  return (__float_as_uint(v) & ~3u) | (ver & 3u);
}
__device__ __forceinline__ float sigm(float x) { return 1.f / (1.f + expf(-x)); }

// gather one tagged 256-vector: lane gets elements 4l..4l+3; retry till all tags match
__device__ __forceinline__ void gather1T(const unsigned* base, int lane, unsigned tag,
                                         float* x) {
  const u64* p = (const u64*)base + 2 * lane;
  for (int it = 0;; ++it) {
    const u64 a = aload64(p), b = aload64(p + 1);
    const bool ok = (((unsigned)a & 3u) == tag) & (((unsigned)(a >> 32) & 3u) == tag) &
                    (((unsigned)b & 3u) == tag) & (((unsigned)(b >> 32) & 3u) == tag);
    if (__ballot(ok) == ~0ull) {
      x[0] = __uint_as_float((unsigned)a); x[1] = __uint_as_float((unsigned)(a >> 32));
      x[2] = __uint_as_float((unsigned)b); x[3] = __uint_as_float((unsigned)(b >> 32));
      return;
    }
    if (it > 48) __builtin_amdgcn_s_sleep(1);
  }
}
// gather two tagged vectors in one combined retry loop
__device__ __forceinline__ void gather2T(const unsigned* b1, unsigned t1,
                                         const unsigned* b2, unsigned t2,
                                         int lane, float* x1, float* x2) {
  const u64* p1 = (const u64*)b1 + 2 * lane;
  const u64* p2 = (const u64*)b2 + 2 * lane;
  for (int it = 0;; ++it) {
    const u64 a = aload64(p1), b = aload64(p1 + 1);
    const u64 c = aload64(p2), d = aload64(p2 + 1);
    const bool ok = (((unsigned)a & 3u) == t1) & (((unsigned)(a >> 32) & 3u) == t1) &
                    (((unsigned)b & 3u) == t1) & (((unsigned)(b >> 32) & 3u) == t1) &
                    (((unsigned)c & 3u) == t2) & (((unsigned)(c >> 32) & 3u) == t2) &
                    (((unsigned)d & 3u) == t2) & (((unsigned)(d >> 32) & 3u) == t2);
    if (__ballot(ok) == ~0ull) {
      x1[0] = __uint_as_float((unsigned)a); x1[1] = __uint_as_float((unsigned)(a >> 32));
      x1[2] = __uint_as_float((unsigned)b); x1[3] = __uint_as_float((unsigned)(b >> 32));
      x2[0] = __uint_as_float((unsigned)c); x2[1] = __uint_as_float((unsigned)(c >> 32));
      x2[2] = __uint_as_float((unsigned)d); x2[3] = __uint_as_float((unsigned)(d >> 32));
      return;
    }
    if (it > 48) __builtin_amdgcn_s_sleep(1);
  }
}
// spin on pre-issued pair of 8B loads until all tags match, then extract
__device__ __forceinline__ void spin4(const u64* p, u64 a, u64 b, unsigned tag, float* x) {
  for (int it = 0;; ++it) {
    const bool ok = (((unsigned)a & 3u) == tag) & (((unsigned)(a >> 32) & 3u) == tag) &
                    (((unsigned)b & 3u) == tag) & (((unsigned)(b >> 32) & 3u) == tag);
    if (__ballot(ok) == ~0ull) break;
    if (it > 40) __builtin_amdgcn_s_sleep(1);
    a = aload64(p); b = aload64(p + 1);
  }
  x[0] = __uint_as_float((unsigned)a); x[1] = __uint_as_float((unsigned)(a >> 32));
  x[2] = __uint_as_float((unsigned)b); x[3] = __uint_as_float((unsigned)(b >> 32));
}

// ---------------- prep: weight transpose + zeroing ----------------
__global__ void prep_kernel(const float* __restrict__ Wu, const float* __restrict__ Wb,
                            const float* __restrict__ Wt, float* __restrict__ ws) {
  const int i0 = blockIdx.x * blockDim.x + threadIdx.x;
  const int st = gridDim.x * blockDim.x;
  for (int i = i0; i < SZ_WCATT; i += st) {
    const int k = i / 600, c = i - 600 * k;
    float v;
    if (c < 100)      v = Wu[c * 330 + k];
    else if (c < 300) { const int q = c - 100; v = Wb[(q % 100) * 660 + (q / 100) * 330 + k]; }
    else              { const int q = c - 300; v = Wt[(q % 100) * 990 + (q / 100) * 330 + k]; }
    ws[O_WCATT + i] = v;
  }
  unsigned* z = (unsigned*)ws + O_STKT;
  for (int i = i0; i < NZERO; i += st) z[i] = 0u;              // zeros with ver-0 tags
  for (int i = i0; i < 2 * HDIM; i += st) {                    // buf zero rows 1024,1025
    ws[O_BUFH + NEDU * HDIM + i] = 0.f;
    ws[O_BUFC + NEDU * HDIM + i] = 0.f;
  }
}

// ---------------- encode (unchanged) ----------------
__global__ __launch_bounds__(256) void encode_kernel(
    const int* __restrict__ edu_words, const int* __restrict__ edu_poses,
    const float* __restrict__ word_emb, const float* __restrict__ pos_emb,
    const float* __restrict__ bu, const float* __restrict__ bb,
    const float* __restrict__ bt, float* __restrict__ ws) {
  __shared__ __align__(16) float xlT[CW * LTOK];
  __shared__ float zl[300 * 21];
  __shared__ float convout[300];
  const int n = blockIdx.x, tid = threadIdx.x;
  const float* WcatT = ws + O_WCATT;

  for (int i = tid; i < LTOK * CW; i += 256) {
    const int l = i / CW, k = i - l * CW;
    float v;
    if (k < 300) v = word_emb[(size_t)edu_words[n * LTOK + l] * 300 + k];
    else         v = pos_emb[(size_t)edu_poses[n * LTOK + l] * 30 + (k - 300)];
    xlT[k * LTOK + l] = v;
  }
  __syncthreads();

  for (int f = tid; f < 300; f += 256) {
    float acc[LTOK];
#pragma unroll
    for (int l = 0; l < LTOK; ++l) acc[l] = 0.f;
    for (int k = 0; k < CW; ++k) {
      const float w = WcatT[k * 600 + f];
      const float4* xp = (const float4*)(xlT + k * LTOK);
      union { float4 v[5]; float s[20]; } xu;
      xu.v[0] = xp[0]; xu.v[1] = xp[1]; xu.v[2] = xp[2]; xu.v[3] = xp[3]; xu.v[4] = xp[4];
#pragma unroll
      for (int l = 0; l < LTOK; ++l) acc[l] += w * xu.s[l];
    }
#pragma unroll
    for (int l = 0; l < LTOK; ++l) zl[f * 21 + l] = acc[l];
  }
  __syncthreads();
  if (tid < 200) {
    float m;
    if (tid < 100) {
      const int f = tid; const float b = bu[f];
      m = zl[f * 21] + b;
      for (int l = 1; l < 20; ++l) m = fmaxf(m, zl[f * 21 + l] + b);
    } else {
      const int f = tid - 100; const float b = bb[f];
      const float* z0 = zl + (100 + f) * 21;
      const float* z1 = zl + (200 + f) * 21;
      m = z1[0] + b;
      for (int u = 1; u <= 19; ++u) m = fmaxf(m, z0[u - 1] + z1[u] + b);
      m = fmaxf(m, z0[19] + b);
    }
    convout[tid] = fmaxf(m, 0.f);
  }
  __syncthreads();

  for (int f = tid; f < 300; f += 256) {
    float acc[LTOK];
#pragma unroll
    for (int l = 0; l < LTOK; ++l) acc[l] = 0.f;
    for (int k = 0; k < CW; ++k) {
      const float w = WcatT[k * 600 + 300 + f];
      const float4* xp = (const float4*)(xlT + k * LTOK);
      union { float4 v[5]; float s[20]; } xu;
      xu.v[0] = xp[0]; xu.v[1] = xp[1]; xu.v[2] = xp[2]; xu.v[3] = xp[3]; xu.v[4] = xp[4];
#pragma unroll
      for (int l = 0; l < LTOK; ++l) acc[l] += w * xu.s[l];
    }
#pragma unroll
    for (int l = 0; l < LTOK; ++l) zl[f * 21 + l] = acc[l];
  }
  __syncthreads();
  if (tid < 100) {
    const int f = tid; const float b = bt[f];
    const float* z0 = zl + f * 21;
    const float* z1 = zl + (100 + f) * 21;
    const float* z2 = zl + (200 + f) * 21;
    float m = z2[0] + b;
    m = fmaxf(m, z1[0] + z2[1] + b);
    for (int u = 2; u <= 19; ++u) m = fmaxf(m, z0[u - 2] + z1[u - 1] + z2[u] + b);
    m = fmaxf(m, z0[18] + z1[19] + b);
    m = fmaxf(m, z0[19] + b);
    convout[200 + f] = fmaxf(m, 0.f);
  }
  __syncthreads();

  float* Fr = ws + O_F + (size_t)n * FEAT;
  for (int j = tid; j < FEAT; j += 256) {
    float v;
    if (j < 300)      v = xlT[j * LTOK + 0];
    else if (j < 600) v = xlT[(j - 300) * LTOK + 19];
    else if (j < 630) v = xlT[(j - 300) * LTOK + 0];
    else              v = convout[j - 630];
    Fr[j] = v;
  }
}

// ---------------- proj (unchanged) ----------------
__global__ __launch_bounds__(256) void proj_kernel(const float* __restrict__ Wp,
                                                   const float* __restrict__ bp,
                                                   float* __restrict__ ws) {
  __shared__ float As[64][17];
  __shared__ float Bs[64][17];
  const float* F = ws + O_F;
  float* bufh = ws + O_BUFH;
  float* bufc = ws + O_BUFC;
  const int tid = threadIdx.x;
  const int m0 = blockIdx.x * 64, n0 = blockIdx.y * 64;
  const int mm0 = (tid & 15) * 4, nn0 = (tid >> 4) * 4;
  float acc[4][4] = {{0.f}};
  for (int k0 = 0; k0 < FEAT; k0 += 16) {
    for (int i = tid; i < 64 * 16; i += 256) {
      const int mm = i >> 4, kk = i & 15;
      const int gk = k0 + kk;
      As[mm][kk] = (gk < FEAT) ? F[(size_t)(m0 + mm) * FEAT + gk] : 0.f;
      Bs[mm][kk] = (gk < FEAT) ? Wp[(size_t)(n0 + mm) * FEAT + gk] : 0.f;
    }
    __syncthreads();
#pragma unroll
    for (int kk = 0; kk < 16; ++kk) {
      float av[4], bv[4];
#pragma unroll
      for (int i = 0; i < 4; ++i) av[i] = As[mm0 + i][kk];
#pragma unroll
      for (int jj = 0; jj < 4; ++jj) bv[jj] = Bs[nn0 + jj][kk];
#pragma unroll
      for (int i = 0; i < 4; ++i)
#pragma unroll
        for (int jj = 0; jj < 4; ++jj) acc[i][jj] += av[i] * bv[jj];
    }
    __syncthreads();
  }
#pragma unroll
  for (int i = 0; i < 4; ++i) {
    const int m = m0 + mm0 + i;
#pragma unroll
    for (int jj = 0; jj < 4; ++jj) {
      const int nn = n0 + nn0 + jj;
      const float v = acc[i][jj] + bp[nn];
      if (nn < 256) bufh[(size_t)m * 256 + nn] = v;
      else          bufc[(size_t)m * 256 + (nn - 256)] = v;
    }
  }
}

// ---------------- parse: barrier-free, one wave per output element ----------------
// 256 WGs x 64 threads. Wave (WG) j owns h-element j: computes all 4 tracker gate rows
// {j,256+j,512+j,768+j} and all 5 compose rows {q*256+j}. No cross-wave exchange ->
// zero barriers in the main loop. Stack slots are parity-double-buffered by version so
// old/new contents coexist (closes the overwrite-while-polling window). Version tables
// (vstk) and stack-c (scs) are WG-private LDS; all WGs run identical control flow so the
// copies evolve identically. th from compose is reused in registers for trackR.
__global__ __launch_bounds__(64, 1) void parse_kernel(
    const int* __restrict__ transes, int nT,
    const float* __restrict__ Wih, const float* __restrict__ Whh,
    const float* __restrict__ bih, const float* __restrict__ bhh,
    const float* __restrict__ Wc, const float* __restrict__ bc,
    const float* __restrict__ Wsc, float* __restrict__ ws) {
  const int lane = threadIdx.x;
  const int j = blockIdx.x;          // owned h-element 0..255

  const float* bufh = ws + O_BUFH;
  const float* bufc = ws + O_BUFC;
  unsigned* stkT = (unsigned*)ws + O_STKT;
  unsigned* thT  = (unsigned*)ws + O_THT;
  float* lossp   = ws + O_LOSSP;

  __shared__ unsigned vstk[MSLOT];
  __shared__ float    scs[MSLOT];
  __shared__ int      trs[2048];

  for (int i = lane; i < MSLOT; i += 64) { vstk[i] = 0u; scs[i] = 0.f; }
  const int nTc = (nT < 2048) ? nT : 2048;
  for (int i = lane; i < nTc; i += 64) trs[i] = transes[i];
  __syncthreads();

  // ---- weight slices: element j, lane covers input cols 4*lane..4*lane+3 ----
  float wt[4][16]; float bt4[4];
#pragma unroll
  for (int g = 0; g < 4; ++g) {
    const int rg = g * 256 + j;
#pragma unroll
    for (int blk = 0; blk < 3; ++blk) {
      const float4 w = *(const float4*)(Wih + (size_t)rg * 768 + blk * 256 + 4 * lane);
      wt[g][4 * blk + 0] = w.x; wt[g][4 * blk + 1] = w.y;
      wt[g][4 * blk + 2] = w.z; wt[g][4 * blk + 3] = w.w;
    }
    const float4 wh = *(const float4*)(Whh + (size_t)rg * 256 + 4 * lane);
    wt[g][12] = wh.x; wt[g][13] = wh.y; wt[g][14] = wh.z; wt[g][15] = wh.w;
    bt4[g] = bih[rg] + bhh[rg];
  }
  float wcm[5][12]; float bc5[5];
#pragma unroll
  for (int q = 0; q < 5; ++q) {
    const int rg = q * 256 + j;
#pragma unroll
    for (int blk = 0; blk < 3; ++blk) {
      const float4 w = *(const float4*)(Wc + (size_t)rg * 768 + blk * 256 + 4 * lane);
      wcm[q][4 * blk + 0] = w.x; wcm[q][4 * blk + 1] = w.y;
      wcm[q][4 * blk + 2] = w.z; wcm[q][4 * blk + 3] = w.w;
    }
    bc5[q] = bc[rg];
  }
  const float ws0 = Wsc[j], ws1 = Wsc[256 + j];

  float tc = 0.f;                 // tracker cell, replicated in all lanes
  unsigned V = 0;
  int sptr = 2, bptr = 0;

  auto bfly4 = [&](float& a0, float& a1, float& a2, float& a3) {
#pragma unroll
    for (int off = 32; off; off >>= 1) {
      a0 += __shfl_xor(a0, off, 64); a1 += __shfl_xor(a1, off, 64);
      a2 += __shfl_xor(a2, off, 64); a3 += __shfl_xor(a3, off, 64);
    }
  };
  auto bfly5 = [&](float& a0, float& a1, float& a2, float& a3, float& a4) {
#pragma unroll
    for (int off = 32; off; off >>= 1) {
      a0 += __shfl_xor(a0, off, 64); a1 += __shfl_xor(a1, off, 64);
      a2 += __shfl_xor(a2, off, 64); a3 += __shfl_xor(a3, off, 64);
      a4 += __shfl_xor(a4, off, 64);
    }
  };

  // finish tracker step: sums are full (all lanes); nonlin redundant in all lanes,
  // lane 0 publishes th (tagged) and the scorer partial pair.
  auto fin_track = [&](float s0, float s1, float s2, float s3) {
    const float gi = s0 + bt4[0], gf = s1 + bt4[1], gg = s2 + bt4[2], go = s3 + bt4[3];
    const float cn = sigm(gf) * tc + sigm(gi) * tanhf(gg);
    tc = cn;
    const float th = sigm(go) * tanhf(cn);
    if (lane == 0) {
      astore(thT + ((V + 1) & 1) * HDIM + j, tagbits(th, V + 1));
      float2 lp; lp.x = ws0 * th; lp.y = ws1 * th;
      *(float2*)(lossp + (size_t)V * 512 + 2 * j) = lp;
    }
  };

  // ---- initial track: p1 = p2 = 0, p3 = buf[0], th = 0 ----
  {
    const float4 f3 = *(const float4*)(bufh + 4 * lane);
    const float x3[4] = { f3.x, f3.y, f3.z, f3.w };
    float s0 = 0.f, s1 = 0.f, s2 = 0.f, s3 = 0.f;
#pragma unroll
    for (int c = 0; c < 4; ++c) {
      s0 += wt[0][8 + c] * x3[c]; s1 += wt[1][8 + c] * x3[c];
      s2 += wt[2][8 + c] * x3[c]; s3 += wt[3][8 + c] * x3[c];
    }
    bfly4(s0, s1, s2, s3);
    fin_track(s0, s1, s2, s3);
    V = 1;
  }

  for (int t = 0; t < nT; ++t) {
    const int tr = (t < 2048) ? trs[t] : transes[t];
    // pre-issue th(V) poll; travels while we do LDS reads / old-slot gathers / statics
    const u64* pt = (const u64*)(thT + (V & 1) * HDIM) + 2 * lane;
    u64 ta = aload64(pt), tb = aload64(pt + 1);
    if (tr) {
      // ==== compose ====
      const unsigned v1 = vstk[sptr - 1], v2 = vstk[sptr - 2];
      const unsigned nvr = v2 + 1;
      const float c1 = scs[sptr - 1], c2 = scs[sptr - 2];
      float h1[4], h2[4];
      gather2T(stkT + (size_t)(v1 & 1) * SZ_BUF + (size_t)(sptr - 1) * HDIM, v1 & 3,
               stkT + (size_t)(v2 & 1) * SZ_BUF + (size_t)(sptr - 2) * HDIM, v2 & 3,
               lane, h1, h2);
      float a0 = 0.f, a1 = 0.f, a2 = 0.f, a3 = 0.f, a4 = 0.f;
#pragma unroll
      for (int c = 0; c < 4; ++c) {
        a0 += wcm[0][c] * h1[c] + wcm[0][4 + c] * h2[c];
        a1 += wcm[1][c] * h1[c] + wcm[1][4 + c] * h2[c];
        a2 += wcm[2][c] * h1[c] + wcm[2][4 + c] * h2[c];
        a3 += wcm[3][c] * h1[c] + wcm[3][4 + c] * h2[c];
        a4 += wcm[4][c] * h1[c] + wcm[4][4 + c] * h2[c];
      }
      float xth[4];
      spin4(pt, ta, tb, V & 3, xth);
#pragma unroll
      for (int c = 0; c < 4; ++c) {
        a0 += wcm[0][8 + c] * xth[c]; a1 += wcm[1][8 + c] * xth[c];
        a2 += wcm[2][8 + c] * xth[c]; a3 += wcm[3][8 + c] * xth[c];
        a4 += wcm[4][8 + c] * xth[c];
      }
      bfly5(a0, a1, a2, a3, a4);
      const float rc = tanhf(a0 + bc5[0]) * sigm(a1 + bc5[1])
                     + sigm(a2 + bc5[2]) * c1 + sigm(a3 + bc5[3]) * c2;
      const float rh = sigm(a4 + bc5[4]) * tanhf(rc);
      const int slot = sptr - 2;
      unsigned* sdst = stkT + (size_t)(nvr & 1) * SZ_BUF + (size_t)slot * HDIM;
      if (lane == 0) {
        astore(sdst + j, tagbits(rh, nvr));    // the rh broadcast (new parity buffer)
        scs[slot] = rc;
        vstk[slot] = nvr;
      }
      // ==== trackR: p1 = rh (spin), p2 = stack[sptr-3], p3 = buf[bptr], th reused ====
      const u64* pr = (const u64*)sdst + 2 * lane;
      u64 ra = aload64(pr), rb = aload64(pr + 1);   // pre-issue rh poll
      const unsigned v3 = vstk[sptr - 3];
      float p2[4];
      gather1T(stkT + (size_t)(v3 & 1) * SZ_BUF + (size_t)(sptr - 3) * HDIM, lane,
               v3 & 3, p2);
      const float4 f3 = *(const float4*)(bufh + (size_t)bptr * HDIM + 4 * lane);
      const float x3[4] = { f3.x, f3.y, f3.z, f3.w };
      float s0 = 0.f, s1 = 0.f, s2 = 0.f, s3 = 0.f;
#pragma unroll
      for (int c = 0; c < 4; ++c) {
        s0 += wt[0][4 + c] * p2[c] + wt[0][8 + c] * x3[c] + wt[0][12 + c] * xth[c];
        s1 += wt[1][4 + c] * p2[c] + wt[1][8 + c] * x3[c] + wt[1][12 + c] * xth[c];
        s2 += wt[2][4 + c] * p2[c] + wt[2][8 + c] * x3[c] + wt[2][12 + c] * xth[c];
        s3 += wt[3][4 + c] * p2[c] + wt[3][8 + c] * x3[c] + wt[3][12 + c] * xth[c];
      }
      float rr[4];
      spin4(pr, ra, rb, nvr & 3, rr);
#pragma unroll
      for (int c = 0; c < 4; ++c) {
        s0 += wt[0][c] * rr[c]; s1 += wt[1][c] * rr[c];
        s2 += wt[2][c] * rr[c]; s3 += wt[3][c] * rr[c];
      }
      bfly4(s0, s1, s2, s3);
      fin_track(s0, s1, s2, s3);
      V += 1; sptr -= 1;
    } else {
      // ==== trackS: push buf[bptr]; p1 = pushed, p2 = stack[sptr-1], p3 = buf[bptr+1] ====
      const unsigned v1 = vstk[sptr - 1];
      const unsigned nv = vstk[sptr] + 1;
      const float4 f1 = *(const float4*)(bufh + (size_t)bptr * HDIM + 4 * lane);
      const float4 f3 = *(const float4*)(bufh + (size_t)(bptr + 1) * HDIM + 4 * lane);
      if (lane == 0) {
        astore(stkT + (size_t)(nv & 1) * SZ_BUF + (size_t)sptr * HDIM + j,
               tagbits(bufh[(size_t)bptr * HDIM + j], nv));
        scs[sptr] = bufc[(size_t)bptr * HDIM + j];
        vstk[sptr] = nv;
      }
      float p2[4];
      gather1T(stkT + (size_t)(v1 & 1) * SZ_BUF + (size_t)(sptr - 1) * HDIM, lane,
               v1 & 3, p2);
      const float x1[4] = { f1.x, f1.y, f1.z, f1.w };
      const float x3[4] = { f3.x, f3.y, f3.z, f3.w };
      float s0 = 0.f, s1 = 0.f, s2 = 0.f, s3 = 0.f;
#pragma unroll
      for (int c = 0; c < 4; ++c) {
        s0 += wt[0][c] * x1[c] + wt[0][4 + c] * p2[c] + wt[0][8 + c] * x3[c];
        s1 += wt[1][c] * x1[c] + wt[1][4 + c] * p2[c] + wt[1][8 + c] * x3[c];
        s2 += wt[2][c] * x1[c] + wt[2][4 + c] * p2[c] + wt[2][8 + c] * x3[c];
        s3 += wt[3][c] * x1[c] + wt[3][4 + c] * p2[c] + wt[3][8 + c] * x3[c];
      }
      float xth[4];
      spin4(pt, ta, tb, V & 3, xth);
#pragma unroll
      for (int c = 0; c < 4; ++c) {
        s0 += wt[0][12 + c] * xth[c]; s1 += wt[1][12 + c] * xth[c];
        s2 += wt[2][12 + c] * xth[c]; s3 += wt[3][12 + c] * xth[c];
      }
      bfly4(s0, s1, s2, s3);
      fin_track(s0, s1, s2, s3);
      V += 1; sptr += 1; bptr += 1;
    }
  }
}

// ---------------- loss reduce: 64-WG partial pass + final pass ----------------
__global__ __launch_bounds__(256) void loss1_kernel(const int* __restrict__ transes, int nT,
                                                    const float* __restrict__ bsc,
                                                    const float* __restrict__ ws,
                                                    double* __restrict__ part) {
  const int tid = threadIdx.x;
  const float* lossp = ws + O_LOSSP;
  __shared__ float r0s[4], r1s[4];
  const float b0 = bsc[0], b1 = bsc[1];
  double acc = 0.0;
  const int t0 = blockIdx.x * 32;
  const int t1 = (t0 + 32 < nT) ? t0 + 32 : nT;
  for (int t = t0; t < t1; ++t) {
    const float2 p = *(const float2*)(lossp + (size_t)t * 512 + 2 * tid);
    float a0 = p.x, a1 = p.y;
#pragma unroll
    for (int off = 32; off; off >>= 1) {
      a0 += __shfl_down(a0, off, 64);
      a1 += __shfl_down(a1, off, 64);
    }
    if ((tid & 63) == 0) { r0s[tid >> 6] = a0; r1s[tid >> 6] = a1; }
    __syncthreads();
    if (tid == 0) {
      const float l0 = r0s[0] + r0s[1] + r0s[2] + r0s[3] + b0;
      const float l1 = r1s[0] + r1s[1] + r1s[2] + r1s[3] + b1;
      const float mx = fmaxf(l0, l1);
      acc += (double)(mx + logf(expf(l0 - mx) + expf(l1 - mx)) - (transes[t] ? l1 : l0));
    }
    __syncthreads();
  }
  if (tid == 0) part[blockIdx.x] = acc;
}

__global__ __launch_bounds__(64) void loss2_kernel(int nT, const double* __restrict__ part,
                                                   float* __restrict__ out) {
  double a = part[threadIdx.x];
#pragma unroll
  for (int off = 32; off; off >>= 1) a += __shfl_down(a, off, 64);
  if (threadIdx.x == 0) out[0] = (float)(a / (double)nT);
}

// ---------------- launch ----------------
extern "C" void kernel_launch(void* const* d_in, const int* in_sizes, int n_in,
                              void* d_out, int out_size, void* d_ws, size_t ws_size,
                              hipStream_t stream) {
  const int*   edu_words = (const int*)d_in[0];
  const int*   edu_poses = (const int*)d_in[1];
  const int*   transes   = (const int*)d_in[2];
  const float* word_emb  = (const float*)d_in[3];
  const float* pos_emb   = (const float*)d_in[4];
  const float* Wu  = (const float*)d_in[5];
  const float* bu  = (const float*)d_in[6];
  const float* Wb  = (const float*)d_in[7];
  const float* bb  = (const float*)d_in[8];
  const float* Wt  = (const float*)d_in[9];
  const float* bt  = (const float*)d_in[10];
  const float* Wp  = (const float*)d_in[11];
  const float* bp  = (const float*)d_in[12];
  const float* Wih = (const float*)d_in[13];
  const float* Whh = (const float*)d_in[14];
  const float* bih = (const float*)d_in[15];
  const float* bhh = (const float*)d_in[16];
  const float* Wc  = (const float*)d_in[17];
  const float* bc  = (const float*)d_in[18];
  const float* Wsc = (const float*)d_in[19];
  const float* bsc = (const float*)d_in[20];
  float* ws  = (float*)d_ws;
  float* out = (float*)d_out;
  int nT = in_sizes[2];

  hipLaunchKernelGGL(prep_kernel, dim3(256), dim3(256), 0, stream, Wu, Wb, Wt, ws);
  hipLaunchKernelGGL(encode_kernel, dim3(NEDU), dim3(256), 0, stream,
                     edu_words, edu_poses, word_emb, pos_emb, bu, bb, bt, ws);
  hipLaunchKernelGGL(proj_kernel, dim3(16, 8), dim3(256), 0, stream, Wp, bp, ws);

  void* args[] = { (void*)&transes, (void*)&nT, (void*)&Wih, (void*)&Whh, (void*)&bih,
                   (void*)&bhh, (void*)&Wc, (void*)&bc, (void*)&Wsc, (void*)&ws };
  hipLaunchCooperativeKernel((const void*)parse_kernel, dim3(256), dim3(64), args, 0, stream);

  double* part = (double*)(ws + O_PART);
  hipLaunchKernelGGL(loss1_kernel, dim3(64), dim3(256), 0, stream, transes, nT, bsc,
                     (const float*)ws, part);
  hipLaunchKernelGGL(loss2_kernel, dim3(1), dim3(64), 0, stream, nT,
                     (const double*)part, out);
}